// Round 1
// baseline (659.849 us; speedup 1.0000x reference)
//
#include <hip/hip_runtime.h>

#define NB  64
#define ND  128
#define NLC 1024
#define NLQ 256
#define FNEG (-1e30f)

// -------------------------------------------------------------------------
// c1[b,l] = sum_d C[b,d,l]*w1[d];  q2[b,m] = sum_d Q[b,d,m]*w2[d]
__global__ __launch_bounds__(256) void bias_kernel(
    const float* __restrict__ C, const float* __restrict__ Q,
    const float* __restrict__ w, float* __restrict__ c1, float* __restrict__ q2) {
  int idx = blockIdx.x * 256 + threadIdx.x;
  if (idx < NB * NLC) {
    int b = idx >> 10;
    int l = idx & (NLC - 1);
    const float* Cb = C + (size_t)b * ND * NLC + l;
    float acc = 0.f;
#pragma unroll 8
    for (int d = 0; d < ND; ++d) acc += Cb[(size_t)d * NLC] * w[d];
    c1[idx] = acc;
  } else {
    int j = idx - NB * NLC;
    int b = j >> 8;
    int m = j & (NLQ - 1);
    const float* Qb = Q + (size_t)b * ND * NLQ + m;
    float acc = 0.f;
#pragma unroll 8
    for (int d = 0; d < ND; ++d) acc += Qb[(size_t)d * NLQ] * w[ND + d];
    q2[j] = acc;
  }
}

// -------------------------------------------------------------------------
// S[b,l,m] = c1[b,l] + q2[b,m] + sum_d (C[b,d,l]*w3[d]) * Q[b,d,m]
// 64x64 tile, K-tile 32 over d. Both operands are K-major -> coalesced loads.
__global__ __launch_bounds__(256) void score_kernel(
    const float* __restrict__ C, const float* __restrict__ Q,
    const float* __restrict__ w, const float* __restrict__ c1,
    const float* __restrict__ q2, float* __restrict__ S) {
  __shared__ float As[32][65];  // [kd][ll] = C*w3
  __shared__ float Bs[32][65];  // [kd][mm] = Q
  int b  = blockIdx.z;
  int l0 = blockIdx.y * 64;
  int m0 = blockIdx.x * 64;
  const float* Cb = C + (size_t)b * ND * NLC;
  const float* Qb = Q + (size_t)b * ND * NLQ;
  const float* w3 = w + 2 * ND;
  int t = threadIdx.x, tx = t & 15, ty = t >> 4;
  float acc[4][4] = {};
  for (int kk = 0; kk < ND; kk += 32) {
#pragma unroll
    for (int i = 0; i < 8; ++i) {
      int idx = t + i * 256;
      int kd = idx >> 6, ll = idx & 63;
      As[kd][ll] = Cb[(size_t)(kk + kd) * NLC + l0 + ll] * w3[kk + kd];
      Bs[kd][ll] = Qb[(size_t)(kk + kd) * NLQ + m0 + ll];
    }
    __syncthreads();
#pragma unroll
    for (int k = 0; k < 32; ++k) {
      float a[4], bb[4];
#pragma unroll
      for (int i = 0; i < 4; ++i) a[i] = As[k][ty + 16 * i];
#pragma unroll
      for (int j = 0; j < 4; ++j) bb[j] = Bs[k][tx + 16 * j];
#pragma unroll
      for (int i = 0; i < 4; ++i)
#pragma unroll
        for (int j = 0; j < 4; ++j) acc[i][j] += a[i] * bb[j];
    }
    __syncthreads();
  }
  float* Sb = S + (size_t)b * NLC * NLQ;
  const float* c1b = c1 + b * NLC;
  const float* q2b = q2 + b * NLQ;
#pragma unroll
  for (int i = 0; i < 4; ++i) {
    int l = l0 + ty + 16 * i;
    float cv = c1b[l];
#pragma unroll
    for (int j = 0; j < 4; ++j) {
      int m = m0 + tx + 16 * j;
      Sb[(size_t)l * NLQ + m] = acc[i][j] + cv + q2b[m];
    }
  }
}

// -------------------------------------------------------------------------
// Row softmax stats over m: rmax[b,l], rscale[b,l]=1/sum(exp)
__global__ __launch_bounds__(256) void rowstat_kernel(
    const float* __restrict__ S, const float* __restrict__ qmask,
    float* __restrict__ rmax, float* __restrict__ rscale) {
  int row  = blockIdx.x * 4 + (threadIdx.x >> 6);  // b*NLC + l
  int lane = threadIdx.x & 63;
  int b = row >> 10;
  const float* Srow = S + (size_t)row * NLQ;
  const float* qm = qmask + b * NLQ;
  float v[4];
  float mx = -INFINITY;
#pragma unroll
  for (int j = 0; j < 4; ++j) {
    int m = lane + 64 * j;
    v[j] = Srow[m] + (1.0f - qm[m]) * FNEG;
    mx = fmaxf(mx, v[j]);
  }
#pragma unroll
  for (int off = 32; off; off >>= 1) mx = fmaxf(mx, __shfl_xor(mx, off));
  float s = 0.f;
#pragma unroll
  for (int j = 0; j < 4; ++j) s += __expf(v[j] - mx);
#pragma unroll
  for (int off = 32; off; off >>= 1) s += __shfl_xor(s, off);
  if (lane == 0) { rmax[row] = mx; rscale[row] = 1.0f / s; }
}

// -------------------------------------------------------------------------
// Column softmax stats over l, partial chunks (online), then combine.
__global__ __launch_bounds__(256) void colstat_kernel(
    const float* __restrict__ S, const float* __restrict__ cmask,
    float* __restrict__ pmax, float* __restrict__ psum) {
  int b = blockIdx.y, chunk = blockIdx.x;  // 8 chunks of 128 l
  int m = threadIdx.x;
  const float* Sb = S + (size_t)b * NLC * NLQ;
  const float* cm = cmask + b * NLC;
  float mx = -INFINITY, s = 0.f;
  for (int i = 0; i < 128; ++i) {
    int l = chunk * 128 + i;
    float v = Sb[(size_t)l * NLQ + m] + (1.0f - cm[l]) * FNEG;
    float nm = fmaxf(mx, v);
    s = s * __expf(mx - nm) + __expf(v - nm);
    mx = nm;
  }
  pmax[(b * 8 + chunk) * NLQ + m] = mx;
  psum[(b * 8 + chunk) * NLQ + m] = s;
}

__global__ __launch_bounds__(256) void colstat_combine_kernel(
    const float* __restrict__ pmax, const float* __restrict__ psum,
    float* __restrict__ cmax, float* __restrict__ cscale) {
  int idx = blockIdx.x * 256 + threadIdx.x;  // b*NLQ + m
  int b = idx >> 8, m = idx & 255;
  float mx = -INFINITY;
#pragma unroll
  for (int c = 0; c < 8; ++c) mx = fmaxf(mx, pmax[(b * 8 + c) * NLQ + m]);
  float s = 0.f;
#pragma unroll
  for (int c = 0; c < 8; ++c)
    s += psum[(b * 8 + c) * NLQ + m] * __expf(pmax[(b * 8 + c) * NLQ + m] - mx);
  cmax[idx] = mx;
  cscale[idx] = 1.0f / s;
}

// -------------------------------------------------------------------------
// T[b,m,d] = cscale[m] * sum_l exp(S[l,m]+mask-cmax[m]) * C[b,d,l]
__global__ __launch_bounds__(256) void tmat_kernel(
    const float* __restrict__ S, const float* __restrict__ C,
    const float* __restrict__ cmask, const float* __restrict__ cmax,
    const float* __restrict__ cscale, float* __restrict__ T) {
  __shared__ float Ss[32][65];  // [kl][mm] = exp(S - cmax)
  __shared__ float Cs[32][65];  // [kl][dd] = Ct
  int b  = blockIdx.z;
  int m0 = blockIdx.y * 64;
  int d0 = blockIdx.x * 64;
  const float* Sb = S + (size_t)b * NLC * NLQ;
  const float* Cb = C + (size_t)b * ND * NLC;
  const float* cm = cmask + b * NLC;
  const float* cmx = cmax + b * NLQ;
  int t = threadIdx.x, tx = t & 15, ty = t >> 4;
  float acc[4][4] = {};
  for (int l0 = 0; l0 < NLC; l0 += 32) {
#pragma unroll
    for (int i = 0; i < 8; ++i) {
      int idx = t + i * 256;
      int kl = idx >> 6, mm = idx & 63;
      float sv = Sb[(size_t)(l0 + kl) * NLQ + m0 + mm];
      Ss[kl][mm] = __expf(sv + (1.0f - cm[l0 + kl]) * FNEG - cmx[m0 + mm]);
      int kl2 = idx & 31, dd = idx >> 5;
      Cs[kl2][dd] = Cb[(size_t)(d0 + dd) * NLC + l0 + kl2];
    }
    __syncthreads();
#pragma unroll
    for (int k = 0; k < 32; ++k) {
      float a[4], bb[4];
#pragma unroll
      for (int i = 0; i < 4; ++i) a[i] = Ss[k][ty + 16 * i];   // over m
#pragma unroll
      for (int j = 0; j < 4; ++j) bb[j] = Cs[k][tx + 16 * j];  // over d
#pragma unroll
      for (int i = 0; i < 4; ++i)
#pragma unroll
        for (int j = 0; j < 4; ++j) acc[i][j] += a[i] * bb[j];
    }
    __syncthreads();
  }
  float* Tb = T + (size_t)b * NLQ * ND;
#pragma unroll
  for (int i = 0; i < 4; ++i) {
    int m = m0 + ty + 16 * i;
    float cs = cscale[b * NLQ + m];
#pragma unroll
    for (int j = 0; j < 4; ++j) {
      int d = d0 + tx + 16 * j;
      Tb[(size_t)m * ND + d] = acc[i][j] * cs;
    }
  }
}

// -------------------------------------------------------------------------
// A = S1 @ Qt; writes out channels [128..255]=A and [256..383]=Ct*A
__global__ __launch_bounds__(256) void amat_kernel(
    const float* __restrict__ S, const float* __restrict__ Q,
    const float* __restrict__ C, const float* __restrict__ qmask,
    const float* __restrict__ rmax, const float* __restrict__ rscale,
    float* __restrict__ out) {
  __shared__ float smem[2 * 64 * 33];
  float (*Ss)[33] = (float(*)[33])smem;              // [ll][km] = exp(S - rmax)
  float (*Qs)[33] = (float(*)[33])(smem + 64 * 33);  // [dd][km] = Qt
  int b  = blockIdx.z;
  int l0 = blockIdx.y * 64;
  int d0 = blockIdx.x * 64;
  const float* Sb = S + (size_t)b * NLC * NLQ;
  const float* Qb = Q + (size_t)b * ND * NLQ;
  const float* Cb = C + (size_t)b * ND * NLC;
  const float* qm = qmask + b * NLQ;
  const float* rmx = rmax + b * NLC;
  int t = threadIdx.x, tx = t & 15, ty = t >> 4;
  float acc[4][4] = {};
  for (int m0 = 0; m0 < NLQ; m0 += 32) {
#pragma unroll
    for (int i = 0; i < 8; ++i) {
      int idx = t + i * 256;
      int ll = idx >> 5, km = idx & 31;
      float sv = Sb[(size_t)(l0 + ll) * NLQ + m0 + km];
      Ss[ll][km] = __expf(sv + (1.0f - qm[m0 + km]) * FNEG - rmx[l0 + ll]);
      Qs[ll][km] = Qb[(size_t)(d0 + ll) * NLQ + m0 + km];  // ll reused as dd
    }
    __syncthreads();
#pragma unroll
    for (int k = 0; k < 32; ++k) {
      float a[4], bb[4];
#pragma unroll
      for (int i = 0; i < 4; ++i) a[i] = Ss[ty + 16 * i][k];
#pragma unroll
      for (int j = 0; j < 4; ++j) bb[j] = Qs[tx + 16 * j][k];
#pragma unroll
      for (int i = 0; i < 4; ++i)
#pragma unroll
        for (int j = 0; j < 4; ++j) acc[i][j] += a[i] * bb[j];
    }
    __syncthreads();
  }
  // transpose through LDS so final writes are coalesced along l
  float (*tr)[65] = (float(*)[65])smem;  // 64*65 = 4160 <= 4224
#pragma unroll
  for (int i = 0; i < 4; ++i) {
    int ll = ty + 16 * i;
    float rs = rscale[b * NLC + l0 + ll];
#pragma unroll
    for (int j = 0; j < 4; ++j) tr[tx + 16 * j][ll] = acc[i][j] * rs;
  }
  __syncthreads();
  float* outb = out + (size_t)b * 4 * ND * NLC;
#pragma unroll
  for (int i = 0; i < 16; ++i) {
    int idx = t + i * 256;
    int dd = idx >> 6, ll = idx & 63;
    float a = tr[dd][ll];
    float c = Cb[(size_t)(d0 + dd) * NLC + l0 + ll];
    outb[(size_t)(128 + d0 + dd) * NLC + l0 + ll] = a;
    outb[(size_t)(256 + d0 + dd) * NLC + l0 + ll] = c * a;
  }
}

// -------------------------------------------------------------------------
// Bv = S1 @ T; writes out channels [0..127]=Ct and [384..511]=Ct*Bv
__global__ __launch_bounds__(256) void bmat_kernel(
    const float* __restrict__ S, const float* __restrict__ T,
    const float* __restrict__ C, const float* __restrict__ qmask,
    const float* __restrict__ rmax, const float* __restrict__ rscale,
    float* __restrict__ out) {
  __shared__ float smem[2 * 64 * 33];
  float (*Ss)[33] = (float(*)[33])smem;              // [ll][km]
  float (*Ts)[65] = (float(*)[65])(smem + 64 * 33);  // [km][dd], 32*65=2080
  int b  = blockIdx.z;
  int l0 = blockIdx.y * 64;
  int d0 = blockIdx.x * 64;
  const float* Sb = S + (size_t)b * NLC * NLQ;
  const float* Tb = T + (size_t)b * NLQ * ND;
  const float* Cb = C + (size_t)b * ND * NLC;
  const float* qm = qmask + b * NLQ;
  const float* rmx = rmax + b * NLC;
  int t = threadIdx.x, tx = t & 15, ty = t >> 4;
  float acc[4][4] = {};
  for (int m0 = 0; m0 < NLQ; m0 += 32) {
#pragma unroll
    for (int i = 0; i < 8; ++i) {
      int idx = t + i * 256;
      int ll = idx >> 5, km = idx & 31;
      float sv = Sb[(size_t)(l0 + ll) * NLQ + m0 + km];
      Ss[ll][km] = __expf(sv + (1.0f - qm[m0 + km]) * FNEG - rmx[l0 + ll]);
      int km2 = idx >> 6, dd = idx & 63;
      Ts[km2][dd] = Tb[(size_t)(m0 + km2) * ND + d0 + dd];
    }
    __syncthreads();
#pragma unroll
    for (int k = 0; k < 32; ++k) {
      float a[4], bb[4];
#pragma unroll
      for (int i = 0; i < 4; ++i) a[i] = Ss[ty + 16 * i][k];
#pragma unroll
      for (int j = 0; j < 4; ++j) bb[j] = Ts[k][tx + 16 * j];
#pragma unroll
      for (int i = 0; i < 4; ++i)
#pragma unroll
        for (int j = 0; j < 4; ++j) acc[i][j] += a[i] * bb[j];
    }
    __syncthreads();
  }
  float (*tr)[65] = (float(*)[65])smem;
#pragma unroll
  for (int i = 0; i < 4; ++i) {
    int ll = ty + 16 * i;
    float rs = rscale[b * NLC + l0 + ll];
#pragma unroll
    for (int j = 0; j < 4; ++j) tr[tx + 16 * j][ll] = acc[i][j] * rs;
  }
  __syncthreads();
  float* outb = out + (size_t)b * 4 * ND * NLC;
#pragma unroll
  for (int i = 0; i < 16; ++i) {
    int idx = t + i * 256;
    int dd = idx >> 6, ll = idx & 63;
    float bv = tr[dd][ll];
    float c = Cb[(size_t)(d0 + dd) * NLC + l0 + ll];
    outb[(size_t)(d0 + dd) * NLC + l0 + ll] = c;
    outb[(size_t)(384 + d0 + dd) * NLC + l0 + ll] = c * bv;
  }
}

// -------------------------------------------------------------------------
extern "C" void kernel_launch(void* const* d_in, const int* in_sizes, int n_in,
                              void* d_out, int out_size, void* d_ws, size_t ws_size,
                              hipStream_t stream) {
  const float* C     = (const float*)d_in[0];
  const float* Q     = (const float*)d_in[1];
  const float* cmask = (const float*)d_in[2];
  const float* qmask = (const float*)d_in[3];
  const float* w     = (const float*)d_in[4];
  float* out = (float*)d_out;
  float* ws  = (float*)d_ws;

  size_t o = 0;
  float* S      = ws + o; o += (size_t)NB * NLC * NLQ;
  float* c1     = ws + o; o += (size_t)NB * NLC;
  float* q2     = ws + o; o += (size_t)NB * NLQ;
  float* rmax   = ws + o; o += (size_t)NB * NLC;
  float* rscale = ws + o; o += (size_t)NB * NLC;
  float* cmax   = ws + o; o += (size_t)NB * NLQ;
  float* cscale = ws + o; o += (size_t)NB * NLQ;
  float* pmax   = ws + o; o += (size_t)NB * 8 * NLQ;
  float* psum   = ws + o; o += (size_t)NB * 8 * NLQ;
  float* T      = ws + o; o += (size_t)NB * NLQ * ND;

  bias_kernel<<<(NB * NLC + NB * NLQ) / 256, 256, 0, stream>>>(C, Q, w, c1, q2);
  score_kernel<<<dim3(NLQ / 64, NLC / 64, NB), 256, 0, stream>>>(C, Q, w, c1, q2, S);
  rowstat_kernel<<<NB * NLC / 4, 256, 0, stream>>>(S, qmask, rmax, rscale);
  colstat_kernel<<<dim3(8, NB), 256, 0, stream>>>(S, cmask, pmax, psum);
  colstat_combine_kernel<<<NB * NLQ / 256, 256, 0, stream>>>(pmax, psum, cmax, cscale);
  tmat_kernel<<<dim3(ND / 64, NLQ / 64, NB), 256, 0, stream>>>(S, C, cmask, cmax, cscale, T);
  amat_kernel<<<dim3(ND / 64, NLC / 64, NB), 256, 0, stream>>>(S, Q, C, qmask, rmax, rscale, out);
  bmat_kernel<<<dim3(ND / 64, NLC / 64, NB), 256, 0, stream>>>(S, T, C, qmask, rmax, rscale, out);
}

// Round 2
// 348.432 us; speedup vs baseline: 1.8938x; 1.8938x over previous
//
#include <hip/hip_runtime.h>

#define NB  64
#define ND  128
#define NLC 1024
#define NLQ 256
#define FNEG (-1e30f)

typedef __bf16 bf16x8 __attribute__((ext_vector_type(8)));
typedef float f32x4 __attribute__((ext_vector_type(4)));

__device__ __forceinline__ ushort f2bf(float x) {
  unsigned u = __float_as_uint(x);
  return (ushort)((u + 0x7fffu + ((u >> 16) & 1u)) >> 16);
}
__device__ __forceinline__ bf16x8 ldfrag(const ushort* p) {
  return *reinterpret_cast<const bf16x8*>(p);
}
__device__ __forceinline__ uint4 pack8(float a0, float a1, float a2, float a3,
                                       float a4, float a5, float a6, float a7) {
  uint4 pk;
  pk.x = (unsigned)f2bf(a0) | ((unsigned)f2bf(a1) << 16);
  pk.y = (unsigned)f2bf(a2) | ((unsigned)f2bf(a3) << 16);
  pk.z = (unsigned)f2bf(a4) | ((unsigned)f2bf(a5) << 16);
  pk.w = (unsigned)f2bf(a6) | ((unsigned)f2bf(a7) << 16);
  return pk;
}

// -------------------------------------------------------------------------
// Transpose prepass: Ctw3[b][l][d] = bf16(C[b][d][l]*w3[d]); Qt16[b][m][d] = bf16(Q[b][d][m])
__global__ __launch_bounds__(256) void convert_kernel(
    const float* __restrict__ C, const float* __restrict__ Q,
    const float* __restrict__ w,
    ushort* __restrict__ Ctw3, ushort* __restrict__ Qt16) {
  __shared__ float tile[64][65];
  int b = blockIdx.y;
  int tid = blockIdx.x;
  int t = threadIdx.x, c = t & 63, r0 = t >> 6;
  if (tid < 32) {
    int d0 = (tid >> 4) * 64, l0 = (tid & 15) * 64;
    const float* src = C + (size_t)b * ND * NLC;
#pragma unroll
    for (int p = 0; p < 16; ++p) {
      int r = r0 + p * 4;
      tile[c][r] = src[(size_t)(d0 + r) * NLC + l0 + c] * w[2 * ND + d0 + r];
    }
    __syncthreads();
    ushort* dst = Ctw3 + (size_t)b * NLC * ND;
#pragma unroll
    for (int p = 0; p < 16; ++p) {
      int r = r0 + p * 4;
      dst[(size_t)(l0 + r) * ND + d0 + c] = f2bf(tile[r][c]);
    }
  } else {
    int q = tid - 32;
    int d0 = (q >> 2) * 64, m0 = (q & 3) * 64;
    const float* src = Q + (size_t)b * ND * NLQ;
#pragma unroll
    for (int p = 0; p < 16; ++p) {
      int r = r0 + p * 4;
      tile[c][r] = src[(size_t)(d0 + r) * NLQ + m0 + c];
    }
    __syncthreads();
    ushort* dst = Qt16 + (size_t)b * NLQ * ND;
#pragma unroll
    for (int p = 0; p < 16; ++p) {
      int r = r0 + p * 4;
      dst[(size_t)(m0 + r) * ND + d0 + c] = f2bf(tile[r][c]);
    }
  }
}

// -------------------------------------------------------------------------
__global__ __launch_bounds__(256) void bias_kernel(
    const float* __restrict__ C, const float* __restrict__ Q,
    const float* __restrict__ w, float* __restrict__ c1, float* __restrict__ q2) {
  int idx = blockIdx.x * 256 + threadIdx.x;
  if (idx < NB * NLC) {
    int b = idx >> 10;
    int l = idx & (NLC - 1);
    const float* Cb = C + (size_t)b * ND * NLC + l;
    float acc = 0.f;
#pragma unroll 8
    for (int d = 0; d < ND; ++d) acc += Cb[(size_t)d * NLC] * w[d];
    c1[idx] = acc;
  } else {
    int j = idx - NB * NLC;
    int b = j >> 8;
    int m = j & (NLQ - 1);
    const float* Qb = Q + (size_t)b * ND * NLQ + m;
    float acc = 0.f;
#pragma unroll 8
    for (int d = 0; d < ND; ++d) acc += Qb[(size_t)d * NLQ] * w[ND + d];
    q2[j] = acc;
  }
}

// -------------------------------------------------------------------------
// S[b][l][m] = c1[l] + q2[m] + MFMA(Ctw3[l,:], Qt16[m,:])  (K = d = 128)
__global__ __launch_bounds__(256) void score_mfma(
    const ushort* __restrict__ Ctw3, const ushort* __restrict__ Qt16,
    const float* __restrict__ c1, const float* __restrict__ q2,
    float* __restrict__ S) {
  __shared__ __align__(16) ushort As[128 * 32];
  __shared__ __align__(16) ushort Bs[128 * 32];
  int b = blockIdx.z;
  int l0 = blockIdx.y * 128, m0 = blockIdx.x * 128;
  const ushort* Ab = Ctw3 + (size_t)b * NLC * ND;
  const ushort* Bb = Qt16 + (size_t)b * NLQ * ND;
  int t = threadIdx.x, lane = t & 63, wid = t >> 6, wy = wid >> 1, wx = wid & 1;
  int ln = lane & 15, qd = lane >> 4;
  f32x4 acc[4][4];
#pragma unroll
  for (int i = 0; i < 4; ++i)
#pragma unroll
    for (int j = 0; j < 4; ++j) acc[i][j] = (f32x4){0.f, 0.f, 0.f, 0.f};

  for (int kk = 0; kk < ND; kk += 32) {
#pragma unroll
    for (int p = 0; p < 2; ++p) {
      int e = t * 8 + p * 2048;
      int r = e >> 5, cc = e & 31;
      *(int4*)(As + e) = *(const int4*)(Ab + (size_t)(l0 + r) * ND + kk + cc);
      *(int4*)(Bs + e) = *(const int4*)(Bb + (size_t)(m0 + r) * ND + kk + cc);
    }
    __syncthreads();
    bf16x8 af[4], bfr[4];
#pragma unroll
    for (int i = 0; i < 4; ++i) {
      af[i]  = ldfrag(As + (wy * 64 + i * 16 + ln) * 32 + qd * 8);
      bfr[i] = ldfrag(Bs + (wx * 64 + i * 16 + ln) * 32 + qd * 8);
    }
#pragma unroll
    for (int i = 0; i < 4; ++i)
#pragma unroll
      for (int j = 0; j < 4; ++j)
        acc[i][j] = __builtin_amdgcn_mfma_f32_16x16x32_bf16(af[i], bfr[j], acc[i][j], 0, 0, 0);
    __syncthreads();
  }
  float* Sb = S + (size_t)b * NLC * NLQ;
  const float* c1b = c1 + b * NLC;
  const float* q2b = q2 + b * NLQ;
#pragma unroll
  for (int j = 0; j < 4; ++j) {
    int m = m0 + wx * 64 + j * 16 + ln;
    float qv = q2b[m];
#pragma unroll
    for (int i = 0; i < 4; ++i)
#pragma unroll
      for (int r = 0; r < 4; ++r) {
        int l = l0 + wy * 64 + i * 16 + qd * 4 + r;
        Sb[(size_t)l * NLQ + m] = acc[i][j][r] + c1b[l] + qv;
      }
  }
}

// -------------------------------------------------------------------------
__global__ __launch_bounds__(256) void rowstat_kernel(
    const float* __restrict__ S, const float* __restrict__ qmask,
    float* __restrict__ rmax, float* __restrict__ rscale) {
  int row  = blockIdx.x * 4 + (threadIdx.x >> 6);
  int lane = threadIdx.x & 63;
  int b = row >> 10;
  const float* Srow = S + (size_t)row * NLQ;
  const float* qm = qmask + b * NLQ;
  float v[4];
  float mx = -INFINITY;
#pragma unroll
  for (int j = 0; j < 4; ++j) {
    int m = lane + 64 * j;
    v[j] = Srow[m] + (1.0f - qm[m]) * FNEG;
    mx = fmaxf(mx, v[j]);
  }
#pragma unroll
  for (int off = 32; off; off >>= 1) mx = fmaxf(mx, __shfl_xor(mx, off));
  float s = 0.f;
#pragma unroll
  for (int j = 0; j < 4; ++j) s += __expf(v[j] - mx);
#pragma unroll
  for (int off = 32; off; off >>= 1) s += __shfl_xor(s, off);
  if (lane == 0) { rmax[row] = mx; rscale[row] = 1.0f / s; }
}

__global__ __launch_bounds__(256) void colstat_kernel(
    const float* __restrict__ S, const float* __restrict__ cmask,
    float* __restrict__ pmax, float* __restrict__ psum) {
  int b = blockIdx.y, chunk = blockIdx.x;
  int m = threadIdx.x;
  const float* Sb = S + (size_t)b * NLC * NLQ;
  const float* cm = cmask + b * NLC;
  float mx = -INFINITY, s = 0.f;
  for (int i = 0; i < 128; ++i) {
    int l = chunk * 128 + i;
    float v = Sb[(size_t)l * NLQ + m] + (1.0f - cm[l]) * FNEG;
    float nm = fmaxf(mx, v);
    s = s * __expf(mx - nm) + __expf(v - nm);
    mx = nm;
  }
  pmax[(b * 8 + chunk) * NLQ + m] = mx;
  psum[(b * 8 + chunk) * NLQ + m] = s;
}

__global__ __launch_bounds__(256) void colstat_combine_kernel(
    const float* __restrict__ pmax, const float* __restrict__ psum,
    const float* __restrict__ qmask,
    float* __restrict__ cmax, float* __restrict__ cscale, float* __restrict__ qneg) {
  int idx = blockIdx.x * 256 + threadIdx.x;
  int b = idx >> 8, m = idx & 255;
  float mx = -INFINITY;
#pragma unroll
  for (int c = 0; c < 8; ++c) mx = fmaxf(mx, pmax[(b * 8 + c) * NLQ + m]);
  float s = 0.f;
#pragma unroll
  for (int c = 0; c < 8; ++c)
    s += psum[(b * 8 + c) * NLQ + m] * __expf(pmax[(b * 8 + c) * NLQ + m] - mx);
  cmax[idx] = mx;
  cscale[idx] = 1.0f / s;
  qneg[idx] = (1.0f - qmask[idx]) * FNEG;
}

// -------------------------------------------------------------------------
// S2eT[b][m][l] = bf16(exp(S[l][m] + (1-cm[l])*NEG - cmax[m]))
__global__ __launch_bounds__(256) void expk(
    const float* __restrict__ S, const float* __restrict__ cmask,
    const float* __restrict__ cmax, ushort* __restrict__ S2eT) {
  __shared__ float tile[64][65];
  int b = blockIdx.z;
  int l0 = blockIdx.y * 64, m0 = blockIdx.x * 64;
  int t = threadIdx.x, c = t & 63, r0 = t >> 6;
  const float* Sb = S + (size_t)b * NLC * NLQ;
  float cmx = cmax[b * NLQ + m0 + c];
#pragma unroll
  for (int p = 0; p < 16; ++p) {
    int r = r0 + p * 4;
    int l = l0 + r;
    float cn = (1.0f - cmask[b * NLC + l]) * FNEG;
    float s = Sb[(size_t)l * NLQ + m0 + c];
    tile[c][r] = __expf(s + cn - cmx);
  }
  __syncthreads();
  ushort* Db = S2eT + (size_t)b * NLQ * NLC;
#pragma unroll
  for (int p = 0; p < 16; ++p) {
    int r = r0 + p * 4;
    Db[(size_t)(m0 + r) * NLC + l0 + c] = f2bf(tile[r][c]);
  }
}

// -------------------------------------------------------------------------
// Tt[b][d][m] = cscale[m] * sum_l bf16(C[d][l]) * S2eT[m][l]   (K = l = 1024)
__global__ __launch_bounds__(256) void tmat_mfma(
    const float* __restrict__ C, const ushort* __restrict__ S2eT,
    const float* __restrict__ cscale, ushort* __restrict__ Tt) {
  __shared__ __align__(16) ushort As[128 * 32];
  __shared__ __align__(16) ushort Bs[64 * 32];
  int b = blockIdx.y;
  int m0 = blockIdx.x * 64;
  const float* Cb = C + (size_t)b * ND * NLC;
  const ushort* Bg = S2eT + (size_t)b * NLQ * NLC;
  int t = threadIdx.x, lane = t & 63, wid = t >> 6, wy = wid >> 1, wx = wid & 1;
  int ln = lane & 15, qd = lane >> 4;
  f32x4 acc[4][2];
#pragma unroll
  for (int i = 0; i < 4; ++i)
#pragma unroll
    for (int j = 0; j < 2; ++j) acc[i][j] = (f32x4){0.f, 0.f, 0.f, 0.f};

  for (int l0 = 0; l0 < NLC; l0 += 32) {
#pragma unroll
    for (int p = 0; p < 2; ++p) {
      int e = t * 8 + p * 2048;
      int r = e >> 5, cc = e & 31;
      const float* sp = Cb + (size_t)r * NLC + l0 + cc;
      float4 v0 = *(const float4*)sp, v1 = *(const float4*)(sp + 4);
      *(uint4*)(As + e) = pack8(v0.x, v0.y, v0.z, v0.w, v1.x, v1.y, v1.z, v1.w);
    }
    {
      int e = t * 8;
      int r = e >> 5, cc = e & 31;
      *(int4*)(Bs + e) = *(const int4*)(Bg + (size_t)(m0 + r) * NLC + l0 + cc);
    }
    __syncthreads();
    bf16x8 af[4], bfr[2];
#pragma unroll
    for (int i = 0; i < 4; ++i) af[i] = ldfrag(As + (wy * 64 + i * 16 + ln) * 32 + qd * 8);
#pragma unroll
    for (int j = 0; j < 2; ++j) bfr[j] = ldfrag(Bs + (wx * 32 + j * 16 + ln) * 32 + qd * 8);
#pragma unroll
    for (int i = 0; i < 4; ++i)
#pragma unroll
      for (int j = 0; j < 2; ++j)
        acc[i][j] = __builtin_amdgcn_mfma_f32_16x16x32_bf16(af[i], bfr[j], acc[i][j], 0, 0, 0);
    __syncthreads();
  }
  ushort* Tb = Tt + (size_t)b * ND * NLQ;
#pragma unroll
  for (int j = 0; j < 2; ++j) {
    int m = m0 + wx * 32 + j * 16 + ln;
    float cs = cscale[b * NLQ + m];
#pragma unroll
    for (int i = 0; i < 4; ++i)
#pragma unroll
      for (int r = 0; r < 4; ++r) {
        int d = wy * 64 + i * 16 + qd * 4 + r;
        Tb[(size_t)d * NLQ + m] = f2bf(acc[i][j][r] * cs);
      }
  }
}

// -------------------------------------------------------------------------
// Fused: Aᵀ[d][l] = sum_m Q[d,m]*e1[l,m];  Bvᵀ[d][l] = sum_m Tt[d,m]*e1[l,m]
// e1 = exp(S + qneg - rmax[l]) computed in staging. Writes all 4 out channel groups.
__global__ __launch_bounds__(256, 2) void outk(
    const float* __restrict__ C, const float* __restrict__ Q,
    const ushort* __restrict__ Tt, const float* __restrict__ S,
    const float* __restrict__ qneg, const float* __restrict__ rmax,
    const float* __restrict__ rscale, float* __restrict__ out) {
  __shared__ __align__(16) ushort As1[128 * 32];
  __shared__ __align__(16) ushort As2[128 * 32];
  __shared__ __align__(16) ushort Bs[128 * 32];
  int b = blockIdx.y;
  int l0 = blockIdx.x * 128;
  const float* Qb = Q + (size_t)b * ND * NLQ;
  const ushort* Tb = Tt + (size_t)b * ND * NLQ;
  const float* Sb = S + (size_t)b * NLC * NLQ;
  const float* qn = qneg + b * NLQ;
  const float* rmx = rmax + b * NLC;
  int t = threadIdx.x, lane = t & 63, wid = t >> 6, wy = wid >> 1, wx = wid & 1;
  int ln = lane & 15, qd = lane >> 4;
  f32x4 acc1[4][4], acc2[4][4];
#pragma unroll
  for (int i = 0; i < 4; ++i)
#pragma unroll
    for (int j = 0; j < 4; ++j) {
      acc1[i][j] = (f32x4){0.f, 0.f, 0.f, 0.f};
      acc2[i][j] = (f32x4){0.f, 0.f, 0.f, 0.f};
    }

  for (int m0 = 0; m0 < NLQ; m0 += 32) {
#pragma unroll
    for (int p = 0; p < 2; ++p) {
      int e = t * 8 + p * 2048;
      int r = e >> 5, cc = e & 31;
      {  // A1 = bf16(Q[d][m])
        const float* sp = Qb + (size_t)r * NLQ + m0 + cc;
        float4 v0 = *(const float4*)sp, v1 = *(const float4*)(sp + 4);
        *(uint4*)(As1 + e) = pack8(v0.x, v0.y, v0.z, v0.w, v1.x, v1.y, v1.z, v1.w);
      }
      // A2 = Tt[d][m] copy
      *(int4*)(As2 + e) = *(const int4*)(Tb + (size_t)r * NLQ + m0 + cc);
      {  // B = exp(S[l][m] + qneg[m] - rmax[l])
        const float* sp = Sb + (size_t)(l0 + r) * NLQ + m0 + cc;
        float4 s0 = *(const float4*)sp, s1 = *(const float4*)(sp + 4);
        float4 q0 = *(const float4*)(qn + m0 + cc), q1 = *(const float4*)(qn + m0 + cc + 4);
        float rm = rmx[l0 + r];
        *(uint4*)(Bs + e) = pack8(
            __expf(s0.x + q0.x - rm), __expf(s0.y + q0.y - rm),
            __expf(s0.z + q0.z - rm), __expf(s0.w + q0.w - rm),
            __expf(s1.x + q1.x - rm), __expf(s1.y + q1.y - rm),
            __expf(s1.z + q1.z - rm), __expf(s1.w + q1.w - rm));
      }
    }
    __syncthreads();
    bf16x8 a1[4], a2[4], bfr[4];
#pragma unroll
    for (int i = 0; i < 4; ++i) {
      a1[i] = ldfrag(As1 + (wy * 64 + i * 16 + ln) * 32 + qd * 8);
      a2[i] = ldfrag(As2 + (wy * 64 + i * 16 + ln) * 32 + qd * 8);
      bfr[i] = ldfrag(Bs + (wx * 64 + i * 16 + ln) * 32 + qd * 8);
    }
#pragma unroll
    for (int i = 0; i < 4; ++i)
#pragma unroll
      for (int j = 0; j < 4; ++j) {
        acc1[i][j] = __builtin_amdgcn_mfma_f32_16x16x32_bf16(a1[i], bfr[j], acc1[i][j], 0, 0, 0);
        acc2[i][j] = __builtin_amdgcn_mfma_f32_16x16x32_bf16(a2[i], bfr[j], acc2[i][j], 0, 0, 0);
      }
    __syncthreads();
  }

  const float* Cb = C + (size_t)b * ND * NLC;
  float* outb = out + (size_t)b * 4 * ND * NLC;
#pragma unroll
  for (int j = 0; j < 4; ++j) {
    int l = l0 + wx * 64 + j * 16 + ln;
    float rs = rscale[b * NLC + l];
#pragma unroll
    for (int i = 0; i < 4; ++i)
#pragma unroll
      for (int r = 0; r < 4; ++r) {
        int d = wy * 64 + i * 16 + qd * 4 + r;
        float a = acc1[i][j][r] * rs;
        float bv = acc2[i][j][r] * rs;
        float c = Cb[(size_t)d * NLC + l];
        outb[(size_t)d * NLC + l] = c;
        outb[(size_t)(128 + d) * NLC + l] = a;
        outb[(size_t)(256 + d) * NLC + l] = c * a;
        outb[(size_t)(384 + d) * NLC + l] = c * bv;
      }
  }
}

// -------------------------------------------------------------------------
extern "C" void kernel_launch(void* const* d_in, const int* in_sizes, int n_in,
                              void* d_out, int out_size, void* d_ws, size_t ws_size,
                              hipStream_t stream) {
  const float* C     = (const float*)d_in[0];
  const float* Q     = (const float*)d_in[1];
  const float* cmask = (const float*)d_in[2];
  const float* qmask = (const float*)d_in[3];
  const float* w     = (const float*)d_in[4];
  float* out = (float*)d_out;

  char* p = (char*)d_ws;
  auto alloc = [&](size_t bytes) { char* r = p; p += (bytes + 255) & ~(size_t)255; return r; };
  float*  S      = (float*)alloc((size_t)NB * NLC * NLQ * 4);
  ushort* Ctw3   = (ushort*)alloc((size_t)NB * NLC * ND * 2);
  ushort* Qt16   = (ushort*)alloc((size_t)NB * NLQ * ND * 2);
  ushort* S2eT   = (ushort*)alloc((size_t)NB * NLQ * NLC * 2);
  ushort* Tt     = (ushort*)alloc((size_t)NB * ND * NLQ * 2);
  float*  c1     = (float*)alloc((size_t)NB * NLC * 4);
  float*  q2     = (float*)alloc((size_t)NB * NLQ * 4);
  float*  rmax   = (float*)alloc((size_t)NB * NLC * 4);
  float*  rscale = (float*)alloc((size_t)NB * NLC * 4);
  float*  cmax   = (float*)alloc((size_t)NB * NLQ * 4);
  float*  cscale = (float*)alloc((size_t)NB * NLQ * 4);
  float*  pmax   = (float*)alloc((size_t)NB * 8 * NLQ * 4);
  float*  psum   = (float*)alloc((size_t)NB * 8 * NLQ * 4);
  float*  qneg   = (float*)alloc((size_t)NB * NLQ * 4);

  convert_kernel<<<dim3(40, NB), 256, 0, stream>>>(C, Q, w, Ctw3, Qt16);
  bias_kernel<<<(NB * NLC + NB * NLQ) / 256, 256, 0, stream>>>(C, Q, w, c1, q2);
  score_mfma<<<dim3(NLQ / 128, NLC / 128, NB), 256, 0, stream>>>(Ctw3, Qt16, c1, q2, S);
  rowstat_kernel<<<NB * NLC / 4, 256, 0, stream>>>(S, qmask, rmax, rscale);
  colstat_kernel<<<dim3(8, NB), 256, 0, stream>>>(S, cmask, pmax, psum);
  colstat_combine_kernel<<<NB * NLQ / 256, 256, 0, stream>>>(pmax, psum, qmask, cmax, cscale, qneg);
  expk<<<dim3(NLQ / 64, NLC / 64, NB), 256, 0, stream>>>(S, cmask, cmax, S2eT);
  tmat_mfma<<<dim3(NLQ / 64, NB), 256, 0, stream>>>(C, S2eT, cscale, Tt);
  outk<<<dim3(NLC / 128, NB), 256, 0, stream>>>(C, Q, Tt, S, qneg, rmax, rscale, out);
}

// Round 3
// 333.699 us; speedup vs baseline: 1.9774x; 1.0441x over previous
//
#include <hip/hip_runtime.h>

#define NB  64
#define ND  128
#define NLC 1024
#define NLQ 256
#define FNEG (-1e30f)

typedef __bf16 bf16x8 __attribute__((ext_vector_type(8)));
typedef float f32x4 __attribute__((ext_vector_type(4)));

__device__ __forceinline__ ushort f2bf(float x) {
  unsigned u = __float_as_uint(x);
  return (ushort)((u + 0x7fffu + ((u >> 16) & 1u)) >> 16);
}
__device__ __forceinline__ float bf2f(ushort u) {
  return __uint_as_float((unsigned)u << 16);
}
__device__ __forceinline__ bf16x8 ldfrag(const ushort* p) {
  return *reinterpret_cast<const bf16x8*>(p);
}
__device__ __forceinline__ uint4 pack8(float a0, float a1, float a2, float a3,
                                       float a4, float a5, float a6, float a7) {
  uint4 pk;
  pk.x = (unsigned)f2bf(a0) | ((unsigned)f2bf(a1) << 16);
  pk.y = (unsigned)f2bf(a2) | ((unsigned)f2bf(a3) << 16);
  pk.z = (unsigned)f2bf(a4) | ((unsigned)f2bf(a5) << 16);
  pk.w = (unsigned)f2bf(a6) | ((unsigned)f2bf(a7) << 16);
  return pk;
}

// -------------------------------------------------------------------------
// Ctw3[b][l][d]=bf16(C*w3) (transpose), Qt16[b][m][d]=bf16(Q) (transpose),
// Cn16[b][d][l]=bf16(C) (pack), Qn16[b][d][m]=bf16(Q) (pack)
__global__ __launch_bounds__(256) void convert_kernel(
    const float* __restrict__ C, const float* __restrict__ Q,
    const float* __restrict__ w,
    ushort* __restrict__ Ctw3, ushort* __restrict__ Qt16,
    ushort* __restrict__ Cn16, ushort* __restrict__ Qn16) {
  __shared__ float tile[64][65];
  int b = blockIdx.y;
  int tid = blockIdx.x;
  int t = threadIdx.x, c = t & 63, r0 = t >> 6;
  if (tid < 32) {
    int d0 = (tid >> 4) * 64, l0 = (tid & 15) * 64;
    const float* src = C + (size_t)b * ND * NLC;
#pragma unroll
    for (int p = 0; p < 16; ++p) {
      int r = r0 + p * 4;
      tile[c][r] = src[(size_t)(d0 + r) * NLC + l0 + c] * w[2 * ND + d0 + r];
    }
    __syncthreads();
    ushort* dst = Ctw3 + (size_t)b * NLC * ND;
#pragma unroll
    for (int p = 0; p < 16; ++p) {
      int r = r0 + p * 4;
      dst[(size_t)(l0 + r) * ND + d0 + c] = f2bf(tile[r][c]);
    }
  } else if (tid < 40) {
    int q = tid - 32;
    int d0 = (q >> 2) * 64, m0 = (q & 3) * 64;
    const float* src = Q + (size_t)b * ND * NLQ;
#pragma unroll
    for (int p = 0; p < 16; ++p) {
      int r = r0 + p * 4;
      tile[c][r] = src[(size_t)(d0 + r) * NLQ + m0 + c];
    }
    __syncthreads();
    ushort* dst = Qt16 + (size_t)b * NLQ * ND;
#pragma unroll
    for (int p = 0; p < 16; ++p) {
      int r = r0 + p * 4;
      dst[(size_t)(m0 + r) * ND + d0 + c] = f2bf(tile[r][c]);
    }
  } else if (tid < 56) {
    // Cn16 straight pack: 16 blocks x 8192 elems
    size_t ofs = (size_t)(tid - 40) * 8192;
    const float* src = C + (size_t)b * ND * NLC + ofs;
    ushort* dst = Cn16 + (size_t)b * ND * NLC + ofs;
#pragma unroll
    for (int it = 0; it < 4; ++it) {
      int e = (it * 256 + t) * 8;
      float4 v0 = *(const float4*)(src + e), v1 = *(const float4*)(src + e + 4);
      *(uint4*)(dst + e) = pack8(v0.x, v0.y, v0.z, v0.w, v1.x, v1.y, v1.z, v1.w);
    }
  } else {
    // Qn16 straight pack: 2 blocks x 16384 elems
    size_t ofs = (size_t)(tid - 56) * 16384;
    const float* src = Q + (size_t)b * ND * NLQ + ofs;
    ushort* dst = Qn16 + (size_t)b * ND * NLQ + ofs;
#pragma unroll
    for (int it = 0; it < 8; ++it) {
      int e = (it * 256 + t) * 8;
      float4 v0 = *(const float4*)(src + e), v1 = *(const float4*)(src + e + 4);
      *(uint4*)(dst + e) = pack8(v0.x, v0.y, v0.z, v0.w, v1.x, v1.y, v1.z, v1.w);
    }
  }
}

// -------------------------------------------------------------------------
__global__ __launch_bounds__(256) void bias_kernel(
    const float* __restrict__ C, const float* __restrict__ Q,
    const float* __restrict__ w, float* __restrict__ c1, float* __restrict__ q2) {
  int idx = blockIdx.x * 256 + threadIdx.x;
  if (idx < NB * NLC) {
    int b = idx >> 10;
    int l = idx & (NLC - 1);
    const float* Cb = C + (size_t)b * ND * NLC + l;
    float acc = 0.f;
#pragma unroll 8
    for (int d = 0; d < ND; ++d) acc += Cb[(size_t)d * NLC] * w[d];
    c1[idx] = acc;
  } else {
    int j = idx - NB * NLC;
    int b = j >> 8;
    int m = j & (NLQ - 1);
    const float* Qb = Q + (size_t)b * ND * NLQ + m;
    float acc = 0.f;
#pragma unroll 8
    for (int d = 0; d < ND; ++d) acc += Qb[(size_t)d * NLQ] * w[ND + d];
    q2[j] = acc;
  }
}

// -------------------------------------------------------------------------
// Fused: S-tile (128 l x 256 m, K=128 MFMA) + biases; row max/sum; e1=bf16
// exp(S+qneg-rmax); column partial sums of e1*exp(rmax+cneg-chunkmax).
__global__ __launch_bounds__(512) void score_stats(
    const ushort* __restrict__ Ctw3, const ushort* __restrict__ Qt16,
    const float* __restrict__ c1, const float* __restrict__ q2,
    const float* __restrict__ cmask, const float* __restrict__ qmask,
    ushort* __restrict__ e1g, float* __restrict__ rmax_g,
    float* __restrict__ rscale_g, float* __restrict__ psum_part,
    float* __restrict__ chunkmax_g) {
  __shared__ union {
    struct { __align__(16) ushort As[128 * 32]; __align__(16) ushort Bs[256 * 32]; } s;
    __align__(16) ushort bounce[128 * 264];
  } u;
  __shared__ float rowred[128][4];
  __shared__ float rowsum[128][4];
  __shared__ float colred[256][2];
  __shared__ float rmaxs[128];
  __shared__ float rcs[128];   // rmax+cneg, then rowfac
  __shared__ float cnegs[128];
  __shared__ float qnegs[256];
  __shared__ float c1s[128];
  __shared__ float q2s[256];
  __shared__ float chunkmax_s;

  int b = blockIdx.y, chunk = blockIdx.x, l0 = chunk * 128;
  int t = threadIdx.x, lane = t & 63, wid = t >> 6;
  int wy = wid >> 2, wx = wid & 3, ln = lane & 15, qd = lane >> 4;

  if (t < 128) {
    c1s[t] = c1[b * NLC + l0 + t];
    cnegs[t] = (1.f - cmask[b * NLC + l0 + t]) * FNEG;
  } else if (t < 384) {
    int m = t - 128;
    q2s[m] = q2[b * NLQ + m];
    qnegs[m] = (1.f - qmask[b * NLQ + m]) * FNEG;
  }

  const ushort* Ab = Ctw3 + (size_t)b * NLC * ND;
  const ushort* Bb = Qt16 + (size_t)b * NLQ * ND;
  f32x4 acc[4][4];
#pragma unroll
  for (int i = 0; i < 4; ++i)
#pragma unroll
    for (int j = 0; j < 4; ++j) acc[i][j] = (f32x4){0.f, 0.f, 0.f, 0.f};

  for (int kk = 0; kk < ND; kk += 32) {
#pragma unroll
    for (int p = 0; p < 3; ++p) {
      int e4 = p * 512 + t;
      if (e4 < 512) {
        int r = e4 >> 2, cc = (e4 & 3) * 8;
        *(int4*)(u.s.As + r * 32 + cc) = *(const int4*)(Ab + (size_t)(l0 + r) * ND + kk + cc);
      } else {
        int e = e4 - 512;
        int r = e >> 2, cc = (e & 3) * 8;
        *(int4*)(u.s.Bs + r * 32 + cc) = *(const int4*)(Bb + (size_t)r * ND + kk + cc);
      }
    }
    __syncthreads();
    bf16x8 af[4], bfr[4];
#pragma unroll
    for (int i = 0; i < 4; ++i) {
      af[i]  = ldfrag(u.s.As + (wy * 64 + i * 16 + ln) * 32 + qd * 8);
      bfr[i] = ldfrag(u.s.Bs + (wx * 64 + i * 16 + ln) * 32 + qd * 8);
    }
#pragma unroll
    for (int i = 0; i < 4; ++i)
#pragma unroll
      for (int j = 0; j < 4; ++j)
        acc[i][j] = __builtin_amdgcn_mfma_f32_16x16x32_bf16(af[i], bfr[j], acc[i][j], 0, 0, 0);
    __syncthreads();
  }

  // add biases; qneg per column
  float qnj[4], q2j[4];
#pragma unroll
  for (int j = 0; j < 4; ++j) {
    int m = wx * 64 + j * 16 + ln;
    qnj[j] = qnegs[m];
    q2j[j] = q2s[m];
  }
#pragma unroll
  for (int i = 0; i < 4; ++i)
#pragma unroll
    for (int r = 0; r < 4; ++r) {
      int ll = wy * 64 + i * 16 + qd * 4 + r;
      float cv = c1s[ll];
#pragma unroll
      for (int j = 0; j < 4; ++j) acc[i][j][r] += cv + q2j[j];
    }

  // row max over m
#pragma unroll
  for (int i = 0; i < 4; ++i)
#pragma unroll
    for (int r = 0; r < 4; ++r) {
      float v = -INFINITY;
#pragma unroll
      for (int j = 0; j < 4; ++j) v = fmaxf(v, acc[i][j][r] + qnj[j]);
      v = fmaxf(v, __shfl_xor(v, 1));
      v = fmaxf(v, __shfl_xor(v, 2));
      v = fmaxf(v, __shfl_xor(v, 4));
      v = fmaxf(v, __shfl_xor(v, 8));
      if (ln == 0) rowred[wy * 64 + i * 16 + qd * 4 + r][wx] = v;
    }
  __syncthreads();
  if (t < 128) {
    float v = fmaxf(fmaxf(rowred[t][0], rowred[t][1]), fmaxf(rowred[t][2], rowred[t][3]));
    rmaxs[t] = v;
    rmax_g[b * NLC + l0 + t] = v;
    rcs[t] = v + cnegs[t];
  }
  __syncthreads();
  if (t < 64) {
    float v = fmaxf(rcs[t], rcs[t + 64]);
    v = fmaxf(v, __shfl_xor(v, 1));
    v = fmaxf(v, __shfl_xor(v, 2));
    v = fmaxf(v, __shfl_xor(v, 4));
    v = fmaxf(v, __shfl_xor(v, 8));
    v = fmaxf(v, __shfl_xor(v, 16));
    v = fmaxf(v, __shfl_xor(v, 32));
    if (t == 0) chunkmax_s = v;
  }
  __syncthreads();
  if (t < 128) rcs[t] = __expf(rcs[t] - chunkmax_s);  // rowfac
  __syncthreads();

  // e1 (overwrite acc), row sums, column partial sums
  float cs[4] = {0.f, 0.f, 0.f, 0.f};
#pragma unroll
  for (int i = 0; i < 4; ++i)
#pragma unroll
    for (int r = 0; r < 4; ++r) {
      int ll = wy * 64 + i * 16 + qd * 4 + r;
      float rmx = rmaxs[ll], rf = rcs[ll];
      float rs = 0.f;
#pragma unroll
      for (int j = 0; j < 4; ++j) {
        float e = __expf(acc[i][j][r] + qnj[j] - rmx);
        acc[i][j][r] = e;
        rs += e;
        cs[j] += e * rf;
      }
      rs += __shfl_xor(rs, 1);
      rs += __shfl_xor(rs, 2);
      rs += __shfl_xor(rs, 4);
      rs += __shfl_xor(rs, 8);
      if (ln == 0) rowsum[ll][wx] = rs;
    }
#pragma unroll
  for (int j = 0; j < 4; ++j) {
    float v = cs[j];
    v += __shfl_xor(v, 16);
    v += __shfl_xor(v, 32);
    if (qd == 0) colred[wx * 64 + j * 16 + ln][wy] = v;
  }
  __syncthreads();
  if (t < 128)
    rscale_g[b * NLC + l0 + t] =
        1.f / (rowsum[t][0] + rowsum[t][1] + rowsum[t][2] + rowsum[t][3]);
  if (t >= 256 && t < 512) {
    int m = t - 256;
    psum_part[(b * 8 + chunk) * NLQ + m] = colred[m][0] + colred[m][1];
  }
  if (t == 0) chunkmax_g[b * 8 + chunk] = chunkmax_s;

  // bounce e1 through LDS for coalesced bf16 stores
#pragma unroll
  for (int i = 0; i < 4; ++i)
#pragma unroll
    for (int r = 0; r < 4; ++r) {
      int ll = wy * 64 + i * 16 + qd * 4 + r;
#pragma unroll
      for (int j = 0; j < 4; ++j)
        u.bounce[ll * 264 + wx * 64 + j * 16 + ln] = f2bf(acc[i][j][r]);
    }
  __syncthreads();
  ushort* Eb = e1g + (size_t)b * NLC * NLQ;
#pragma unroll
  for (int p = 0; p < 8; ++p) {
    int idx4 = p * 512 + t;
    int r = idx4 >> 5, c = (idx4 & 31) * 8;
    *(int4*)(Eb + (size_t)(l0 + r) * NLQ + c) = *(const int4*)(u.bounce + r * 264 + c);
  }
}

// -------------------------------------------------------------------------
__global__ __launch_bounds__(256) void stat_combine(
    const float* __restrict__ psum_part, const float* __restrict__ chunkmax_g,
    const float* __restrict__ rmax_g, const float* __restrict__ cmask,
    float* __restrict__ cinv, float* __restrict__ gfac) {
  __shared__ float cm[8];
  int b = blockIdx.x, t = threadIdx.x;
  if (t < 8) cm[t] = chunkmax_g[b * 8 + t];
  __syncthreads();
  float K = cm[0];
#pragma unroll
  for (int c = 1; c < 8; ++c) K = fmaxf(K, cm[c]);
  {
    float s = 0.f;
#pragma unroll
    for (int c = 0; c < 8; ++c)
      s += psum_part[(b * 8 + c) * NLQ + t] * __expf(cm[c] - K);
    cinv[b * NLQ + t] = 1.f / s;
  }
#pragma unroll
  for (int it = 0; it < 4; ++it) {
    int l = it * 256 + t;
    gfac[b * NLC + l] =
        __expf(rmax_g[b * NLC + l] + (1.f - cmask[b * NLC + l]) * FNEG - K);
  }
}

// -------------------------------------------------------------------------
// Tpart[b][ks][d][m] = sum_{l in ks-split} Cn16[d][l] * (e1[l][m]*gfac[l])
__global__ __launch_bounds__(512) void tmat_mfma(
    const ushort* __restrict__ Cn16, const ushort* __restrict__ e1g,
    const float* __restrict__ gfac, float* __restrict__ Tpart) {
  __shared__ __align__(16) ushort As[128 * 32];
  __shared__ __align__(16) ushort Bs[256 * 40];
  int b = blockIdx.y, ks = blockIdx.x;
  int t = threadIdx.x, lane = t & 63, wid = t >> 6;
  int wy = wid >> 2, wx = wid & 3, ln = lane & 15, qd = lane >> 4;
  const ushort* Cb = Cn16 + (size_t)b * ND * NLC;
  const ushort* Eb = e1g + (size_t)b * NLC * NLQ;
  const float* Gb = gfac + b * NLC;
  f32x4 acc[4][4];
#pragma unroll
  for (int i = 0; i < 4; ++i)
#pragma unroll
    for (int j = 0; j < 4; ++j) acc[i][j] = (f32x4){0.f, 0.f, 0.f, 0.f};

  for (int c0 = 0; c0 < 256; c0 += 32) {
    int l0 = ks * 256 + c0;
    {
      int r = t >> 2, cc = (t & 3) * 8;
      *(int4*)(As + r * 32 + cc) = *(const int4*)(Cb + (size_t)r * NLC + l0 + cc);
    }
#pragma unroll
    for (int p = 0; p < 2; ++p) {
      int e4 = p * 512 + t;
      int r = e4 >> 5, c8 = (e4 & 31) * 8;
      int4 v = *(const int4*)(Eb + (size_t)(l0 + r) * NLQ + c8);
      float rf = Gb[l0 + r];
      const ushort* sv = (const ushort*)&v;
#pragma unroll
      for (int k = 0; k < 8; ++k)
        Bs[(c8 + k) * 40 + r] = f2bf(bf2f(sv[k]) * rf);
    }
    __syncthreads();
    bf16x8 af[4], bfr[4];
#pragma unroll
    for (int i = 0; i < 4; ++i) {
      af[i]  = ldfrag(As + (wy * 64 + i * 16 + ln) * 32 + qd * 8);
      bfr[i] = ldfrag(Bs + (wx * 64 + i * 16 + ln) * 40 + qd * 8);
    }
#pragma unroll
    for (int i = 0; i < 4; ++i)
#pragma unroll
      for (int j = 0; j < 4; ++j)
        acc[i][j] = __builtin_amdgcn_mfma_f32_16x16x32_bf16(af[i], bfr[j], acc[i][j], 0, 0, 0);
    __syncthreads();
  }
  float* Tb = Tpart + ((size_t)(b * 4 + ks)) * ND * NLQ;
#pragma unroll
  for (int i = 0; i < 4; ++i)
#pragma unroll
    for (int r = 0; r < 4; ++r) {
      int d = wy * 64 + i * 16 + qd * 4 + r;
#pragma unroll
      for (int j = 0; j < 4; ++j) {
        int m = wx * 64 + j * 16 + ln;
        Tb[(size_t)d * NLQ + m] = acc[i][j][r];
      }
    }
}

// -------------------------------------------------------------------------
__global__ __launch_bounds__(256) void tcombine(
    const float* __restrict__ Tpart, const float* __restrict__ cinv,
    ushort* __restrict__ Tt) {
  int gid = blockIdx.x * 256 + threadIdx.x;
  int e = gid * 4;
  int b = e >> 15;
  int r = e & 32767;
  int m = r & 255;
  float4 s = {0.f, 0.f, 0.f, 0.f};
#pragma unroll
  for (int ks = 0; ks < 4; ++ks) {
    float4 v = *(const float4*)(Tpart + ((size_t)(b * 4 + ks)) * ND * NLQ + r);
    s.x += v.x; s.y += v.y; s.z += v.z; s.w += v.w;
  }
  float4 ci = *(const float4*)(cinv + b * NLQ + m);
  ushort4 o;
  o.x = f2bf(s.x * ci.x); o.y = f2bf(s.y * ci.y);
  o.z = f2bf(s.z * ci.z); o.w = f2bf(s.w * ci.w);
  *(ushort4*)(Tt + (size_t)b * ND * NLQ + r) = o;
}

// -------------------------------------------------------------------------
// A[d][l] = sum_m Qn16[d][m]*e1[l][m]; Bv[d][l] = sum_m Tt[d][m]*e1[l][m];
// scale by rscale[l]; write all 4 output channel groups.
__global__ __launch_bounds__(256, 2) void outk(
    const float* __restrict__ C, const ushort* __restrict__ Qn16,
    const ushort* __restrict__ Tt, const ushort* __restrict__ e1g,
    const float* __restrict__ rscale, float* __restrict__ out) {
  __shared__ __align__(16) ushort As1[128 * 32];
  __shared__ __align__(16) ushort As2[128 * 32];
  __shared__ __align__(16) ushort Bs[128 * 32];
  int b = blockIdx.y;
  int l0 = blockIdx.x * 128;
  const ushort* Qb = Qn16 + (size_t)b * ND * NLQ;
  const ushort* Tb = Tt + (size_t)b * ND * NLQ;
  const ushort* Eb = e1g + (size_t)b * NLC * NLQ;
  int t = threadIdx.x, lane = t & 63, wid = t >> 6, wy = wid >> 1, wx = wid & 1;
  int ln = lane & 15, qd = lane >> 4;
  f32x4 acc1[4][4], acc2[4][4];
#pragma unroll
  for (int i = 0; i < 4; ++i)
#pragma unroll
    for (int j = 0; j < 4; ++j) {
      acc1[i][j] = (f32x4){0.f, 0.f, 0.f, 0.f};
      acc2[i][j] = (f32x4){0.f, 0.f, 0.f, 0.f};
    }

  for (int m0 = 0; m0 < NLQ; m0 += 32) {
#pragma unroll
    for (int p = 0; p < 2; ++p) {
      int e = t * 8 + p * 2048;
      int r = e >> 5, cc = e & 31;
      *(int4*)(As1 + e) = *(const int4*)(Qb + (size_t)r * NLQ + m0 + cc);
      *(int4*)(As2 + e) = *(const int4*)(Tb + (size_t)r * NLQ + m0 + cc);
      *(int4*)(Bs + e)  = *(const int4*)(Eb + (size_t)(l0 + r) * NLQ + m0 + cc);
    }
    __syncthreads();
    bf16x8 a1[4], a2[4], bfr[4];
#pragma unroll
    for (int i = 0; i < 4; ++i) {
      a1[i] = ldfrag(As1 + (wy * 64 + i * 16 + ln) * 32 + qd * 8);
      a2[i] = ldfrag(As2 + (wy * 64 + i * 16 + ln) * 32 + qd * 8);
      bfr[i] = ldfrag(Bs + (wx * 64 + i * 16 + ln) * 32 + qd * 8);
    }
#pragma unroll
    for (int i = 0; i < 4; ++i)
#pragma unroll
      for (int j = 0; j < 4; ++j) {
        acc1[i][j] = __builtin_amdgcn_mfma_f32_16x16x32_bf16(a1[i], bfr[j], acc1[i][j], 0, 0, 0);
        acc2[i][j] = __builtin_amdgcn_mfma_f32_16x16x32_bf16(a2[i], bfr[j], acc2[i][j], 0, 0, 0);
      }
    __syncthreads();
  }

  const float* Cb = C + (size_t)b * ND * NLC;
  float* outb = out + (size_t)b * 4 * ND * NLC;
#pragma unroll
  for (int j = 0; j < 4; ++j) {
    int l = l0 + wx * 64 + j * 16 + ln;
    float rs = rscale[b * NLC + l];
#pragma unroll
    for (int i = 0; i < 4; ++i)
#pragma unroll
      for (int r = 0; r < 4; ++r) {
        int d = wy * 64 + i * 16 + qd * 4 + r;
        float a = acc1[i][j][r] * rs;
        float bv = acc2[i][j][r] * rs;
        float c = Cb[(size_t)d * NLC + l];
        outb[(size_t)d * NLC + l] = c;
        outb[(size_t)(128 + d) * NLC + l] = a;
        outb[(size_t)(256 + d) * NLC + l] = c * a;
        outb[(size_t)(384 + d) * NLC + l] = c * bv;
      }
  }
}

// -------------------------------------------------------------------------
extern "C" void kernel_launch(void* const* d_in, const int* in_sizes, int n_in,
                              void* d_out, int out_size, void* d_ws, size_t ws_size,
                              hipStream_t stream) {
  const float* C     = (const float*)d_in[0];
  const float* Q     = (const float*)d_in[1];
  const float* cmask = (const float*)d_in[2];
  const float* qmask = (const float*)d_in[3];
  const float* w     = (const float*)d_in[4];
  float* out = (float*)d_out;

  char* p = (char*)d_ws;
  auto alloc = [&](size_t bytes) { char* r = p; p += (bytes + 255) & ~(size_t)255; return r; };
  ushort* e1g    = (ushort*)alloc((size_t)NB * NLC * NLQ * 2);
  ushort* Ctw3   = (ushort*)alloc((size_t)NB * NLC * ND * 2);
  ushort* Qt16   = (ushort*)alloc((size_t)NB * NLQ * ND * 2);
  ushort* Cn16   = (ushort*)alloc((size_t)NB * ND * NLC * 2);
  ushort* Qn16   = (ushort*)alloc((size_t)NB * ND * NLQ * 2);
  float*  Tpart  = (float*)alloc((size_t)NB * 4 * ND * NLQ * 4);
  ushort* Tt     = (ushort*)alloc((size_t)NB * ND * NLQ * 2);
  float*  c1     = (float*)alloc((size_t)NB * NLC * 4);
  float*  q2     = (float*)alloc((size_t)NB * NLQ * 4);
  float*  rmax   = (float*)alloc((size_t)NB * NLC * 4);
  float*  rscale = (float*)alloc((size_t)NB * NLC * 4);
  float*  gfac   = (float*)alloc((size_t)NB * NLC * 4);
  float*  cinv   = (float*)alloc((size_t)NB * NLQ * 4);
  float*  psum   = (float*)alloc((size_t)NB * 8 * NLQ * 4);
  float*  chmax  = (float*)alloc((size_t)NB * 8 * 4);

  convert_kernel<<<dim3(58, NB), 256, 0, stream>>>(C, Q, w, Ctw3, Qt16, Cn16, Qn16);
  bias_kernel<<<(NB * NLC + NB * NLQ) / 256, 256, 0, stream>>>(C, Q, w, c1, q2);
  score_stats<<<dim3(NLC / 128, NB), 512, 0, stream>>>(
      Ctw3, Qt16, c1, q2, cmask, qmask, e1g, rmax, rscale, psum, chmax);
  stat_combine<<<NB, 256, 0, stream>>>(psum, chmax, rmax, cmask, cinv, gfac);
  tmat_mfma<<<dim3(4, NB), 512, 0, stream>>>(Cn16, e1g, gfac, Tpart);
  tcombine<<<(NB * ND * NLQ / 4) / 256, 256, 0, stream>>>(Tpart, cinv, Tt);
  outk<<<dim3(NLC / 128, NB), 256, 0, stream>>>(C, Qn16, Tt, e1g, rscale, out);
}